// Round 6
// baseline (159.019 us; speedup 1.0000x reference)
//
#include <hip/hip_runtime.h>

typedef __attribute__((ext_vector_type(8))) short short8;
typedef __attribute__((ext_vector_type(4))) float f32x4;

#define B_ 2
#define S_ 512
#define D_ 768
#define NH 12
#define HD 64

__device__ inline short f2bf(float f) {
    union { float f; unsigned u; } v; v.f = f;
    unsigned r = v.u + 0x7fffu + ((v.u >> 16) & 1u);
    return (short)(r >> 16);
}

// ---------------------------------------------------------------------------
// Kernel 1: QKV projection, bf16 MFMA (16x16x32), fp32 accumulate.
// q -> qbf (bf16, pre-scaled 1/8), k -> kbf (bf16), v -> vws (fp32),
// all in (B, NH, S, HD) layout.
// ---------------------------------------------------------------------------
__global__ __launch_bounds__(256) void qkv_gemm(
    const float* __restrict__ hidden,
    const float* __restrict__ Wq, const float* __restrict__ Wk, const float* __restrict__ Wv,
    const float* __restrict__ bq, const float* __restrict__ bk, const float* __restrict__ bv,
    short* __restrict__ qbf, short* __restrict__ kbf, float* __restrict__ vws)
{
    __shared__ short hs[64 * 72];
    __shared__ short wt[64 * 72];

    const int mt = blockIdx.x, nt = blockIdx.y, mat = blockIdx.z;
    const int m0 = mt * 64, n0 = nt * 64;
    const float* W    = (mat == 0) ? Wq : ((mat == 1) ? Wk : Wv);
    const float* bias = (mat == 0) ? bq : ((mat == 1) ? bk : bv);

    const int tid = threadIdx.x;
    const int w = tid >> 6, l = tid & 63;
    const int sr = tid >> 2, sc = (tid & 3) * 16;

    f32x4 acc[4];
    #pragma unroll
    for (int i = 0; i < 4; ++i) acc[i] = (f32x4){0.f, 0.f, 0.f, 0.f};

    const int arow = (w * 16 + (l & 15)) * 72 + (l >> 4) * 8;

    for (int kt = 0; kt < 12; ++kt) {
        const int d0 = kt * 64;
        if (kt) __syncthreads();
        {
            const float4* sa = (const float4*)(hidden + (size_t)(m0 + sr) * D_ + d0 + sc);
            float4 x0 = sa[0], x1 = sa[1], x2 = sa[2], x3 = sa[3];
            short8 p0 = {f2bf(x0.x), f2bf(x0.y), f2bf(x0.z), f2bf(x0.w),
                         f2bf(x1.x), f2bf(x1.y), f2bf(x1.z), f2bf(x1.w)};
            short8 p1 = {f2bf(x2.x), f2bf(x2.y), f2bf(x2.z), f2bf(x2.w),
                         f2bf(x3.x), f2bf(x3.y), f2bf(x3.z), f2bf(x3.w)};
            *(short8*)&hs[sr * 72 + sc]     = p0;
            *(short8*)&hs[sr * 72 + sc + 8] = p1;
            const float4* sb = (const float4*)(W + (size_t)(n0 + sr) * D_ + d0 + sc);
            float4 y0 = sb[0], y1 = sb[1], y2 = sb[2], y3 = sb[3];
            short8 q0 = {f2bf(y0.x), f2bf(y0.y), f2bf(y0.z), f2bf(y0.w),
                         f2bf(y1.x), f2bf(y1.y), f2bf(y1.z), f2bf(y1.w)};
            short8 q1 = {f2bf(y2.x), f2bf(y2.y), f2bf(y2.z), f2bf(y2.w),
                         f2bf(y3.x), f2bf(y3.y), f2bf(y3.z), f2bf(y3.w)};
            *(short8*)&wt[sr * 72 + sc]     = q0;
            *(short8*)&wt[sr * 72 + sc + 8] = q1;
        }
        __syncthreads();
        short8 a0 = *(const short8*)&hs[arow];
        short8 a1 = *(const short8*)&hs[arow + 32];
        #pragma unroll
        for (int ct = 0; ct < 4; ++ct) {
            const int brow = (ct * 16 + (l & 15)) * 72 + (l >> 4) * 8;
            short8 b0 = *(const short8*)&wt[brow];
            short8 b1 = *(const short8*)&wt[brow + 32];
            acc[ct] = __builtin_amdgcn_mfma_f32_16x16x32_bf16(a0, b0, acc[ct], 0, 0, 0);
            acc[ct] = __builtin_amdgcn_mfma_f32_16x16x32_bf16(a1, b1, acc[ct], 0, 0, 0);
        }
    }

    #pragma unroll
    for (int ct = 0; ct < 4; ++ct) {
        #pragma unroll
        for (int rr = 0; rr < 4; ++rr) {
            const int m_l = w * 16 + (l >> 4) * 4 + rr;
            const int n_l = ct * 16 + (l & 15);
            const int m = m0 + m_l;
            const int b = m >> 9, s = m & 511;
            float v = acc[ct][rr] + bias[n0 + n_l];
            const size_t dst = (((size_t)(b * NH + nt) * S_) + s) * HD + n_l;
            if (mat == 0)      qbf[dst] = f2bf(v * 0.125f);
            else if (mat == 1) kbf[dst] = f2bf(v);
            else               vws[dst] = v;
        }
    }
}

// ---------------------------------------------------------------------------
// Kernel 2: scores = qs . K^T + mask, batched over (b,n). 64x64 tile.
// Output layout (b, n, s, k).
// ---------------------------------------------------------------------------
__global__ __launch_bounds__(256) void score_qk(
    const short* __restrict__ qbf, const short* __restrict__ kbf,
    const float* __restrict__ mask, float* __restrict__ scores)
{
    __shared__ short qa[64 * 72];
    __shared__ short kb[64 * 72];

    const int st = blockIdx.x, ktile = blockIdx.y, z = blockIdx.z;
    const int b = z / NH, n = z % NH;
    const int s0 = st * 64, k0 = ktile * 64;
    const int tid = threadIdx.x;
    const int w = tid >> 6, l = tid & 63;
    const int sr = tid >> 2, sc = (tid & 3) * 16;

    {
        const short8* sa = (const short8*)(qbf + (((size_t)(b * NH + n) * S_) + s0 + sr) * HD + sc);
        *(short8*)&qa[sr * 72 + sc]     = sa[0];
        *(short8*)&qa[sr * 72 + sc + 8] = sa[1];
        const short8* sb = (const short8*)(kbf + (((size_t)(b * NH + n) * S_) + k0 + sr) * HD + sc);
        *(short8*)&kb[sr * 72 + sc]     = sb[0];
        *(short8*)&kb[sr * 72 + sc + 8] = sb[1];
    }
    __syncthreads();

    f32x4 acc[4];
    #pragma unroll
    for (int i = 0; i < 4; ++i) acc[i] = (f32x4){0.f, 0.f, 0.f, 0.f};

    const int arow = (w * 16 + (l & 15)) * 72 + (l >> 4) * 8;
    short8 a0 = *(const short8*)&qa[arow];
    short8 a1 = *(const short8*)&qa[arow + 32];
    #pragma unroll
    for (int ct = 0; ct < 4; ++ct) {
        const int brow = (ct * 16 + (l & 15)) * 72 + (l >> 4) * 8;
        short8 b0 = *(const short8*)&kb[brow];
        short8 b1 = *(const short8*)&kb[brow + 32];
        acc[ct] = __builtin_amdgcn_mfma_f32_16x16x32_bf16(a0, b0, acc[ct], 0, 0, 0);
        acc[ct] = __builtin_amdgcn_mfma_f32_16x16x32_bf16(a1, b1, acc[ct], 0, 0, 0);
    }

    #pragma unroll
    for (int ct = 0; ct < 4; ++ct) {
        const float mv = mask[b * S_ + k0 + ct * 16 + (l & 15)];
        #pragma unroll
        for (int rr = 0; rr < 4; ++rr) {
            const int s_l = w * 16 + (l >> 4) * 4 + rr;
            scores[(((size_t)(b * NH + n) * S_) + s0 + s_l) * S_ + k0 + ct * 16 + (l & 15)]
                = acc[ct][rr] + mv;
        }
    }
}

// ---------------------------------------------------------------------------
// Kernel 3: rel contribution, streaming-window version.
// 1024 blocks x 256 threads = 4096 waves. Superunit su = one (b,s,sk) tile of
// 16 k-rows x 64 h (4KB/tensor). su = g*4096 + gwid: ALL waves march in
// lockstep through rel linearly (copy-like moving window -> DRAM row
// locality). Per superiter: 12 dense 1KB loads (pipelined one ahead),
// rsum -> bf16 -> per-wave LDS slab, 2 MFMA vs q A-fragment, plain stores
// to relsc (b,s,n,k). No barriers, no RMW.
// ---------------------------------------------------------------------------
__global__ __launch_bounds__(256, 3) void score_rel(
    const short* __restrict__ qbf,
    const float* __restrict__ rel1, const float* __restrict__ rel2, const float* __restrict__ rel3,
    float* __restrict__ relsc)
{
    __shared__ short lds[4][16 * 80];   // per-wave 2.5KB slab, stride 80 shorts

    const int tid = threadIdx.x;
    const int w  = tid >> 6, l = tid & 63;
    const int gw = blockIdx.x * 4 + w;   // 0..4095
    const int lr = l >> 4;               // 0..3
    const int hq = l & 15;               // 0..15

    short* slab = &lds[w][0];

    float4 r1v[4], r2v[4], r3v[4];
    float4 n1v[4], n2v[4], n3v[4];

    {
        const size_t base = (size_t)gw * 1024 + (size_t)(lr * 64 + hq * 4);
        #pragma unroll
        for (int j = 0; j < 4; ++j) {
            r1v[j] = *(const float4*)(rel1 + base + j * 256);
            r2v[j] = *(const float4*)(rel2 + base + j * 256);
            r3v[j] = *(const float4*)(rel3 + base + j * 256);
        }
    }

    for (int g = 0; g < 8; ++g) {
        const int su = g * 4096 + gw;
        const int b  = su >> 14;
        const int s  = (su >> 5) & 511;
        const int sk = su & 31;

        // Prefetch next superunit (moving window stays lockstep).
        if (g < 7) {
            const size_t base = (size_t)(su + 4096) * 1024 + (size_t)(lr * 64 + hq * 4);
            #pragma unroll
            for (int j = 0; j < 4; ++j) {
                n1v[j] = *(const float4*)(rel1 + base + j * 256);
                n2v[j] = *(const float4*)(rel2 + base + j * 256);
                n3v[j] = *(const float4*)(rel3 + base + j * 256);
            }
        }

        // q A-fragment for (b, s): row n = hq (rows 12..15 clamp, unused).
        const int nq = (hq < NH) ? hq : 0;
        const short* qp = qbf + (((size_t)(b * NH + nq) * S_) + s) * HD;
        short8 a0 = *(const short8*)(qp + lr * 8);
        short8 a1 = *(const short8*)(qp + lr * 8 + 32);

        // rsum -> bf16 -> LDS slab (row j*4+lr, h-chunk hq*4).
        #pragma unroll
        for (int j = 0; j < 4; ++j) {
            float4 x = r1v[j], y = r2v[j], z = r3v[j];
            float sx = x.x + y.x + z.x;
            float sy = x.y + y.y + z.y;
            float sz = x.z + y.z + z.z;
            float sw = x.w + y.w + z.w;
            unsigned lo = (unsigned)(unsigned short)f2bf(sx) | ((unsigned)(unsigned short)f2bf(sy) << 16);
            unsigned hi = (unsigned)(unsigned short)f2bf(sz) | ((unsigned)(unsigned short)f2bf(sw) << 16);
            uint2 pk; pk.x = lo; pk.y = hi;
            *(uint2*)&slab[(j * 4 + lr) * 80 + hq * 4] = pk;
        }

        // B fragments from slab (wave-local: lgkmcnt ordering, no barrier).
        short8 b0 = *(const short8*)&slab[hq * 80 + lr * 8];
        short8 b1 = *(const short8*)&slab[hq * 80 + 32 + lr * 8];

        f32x4 acc = (f32x4){0.f, 0.f, 0.f, 0.f};
        acc = __builtin_amdgcn_mfma_f32_16x16x32_bf16(a0, b0, acc, 0, 0, 0);
        acc = __builtin_amdgcn_mfma_f32_16x16x32_bf16(a1, b1, acc, 0, 0, 0);

        // Store: n = lr*4+rr, k = sk*16 + hq. relsc layout (b, s, n, k).
        #pragma unroll
        for (int rr = 0; rr < 4; ++rr) {
            const int n = lr * 4 + rr;
            if (n < NH)
                relsc[(((size_t)(b * S_ + s)) * NH + n) * S_ + sk * 16 + hq] = acc[rr];
        }

        if (g < 7) {
            #pragma unroll
            for (int j = 0; j < 4; ++j) { r1v[j] = n1v[j]; r2v[j] = n2v[j]; r3v[j] = n3v[j]; }
        }
    }
}

// ---------------------------------------------------------------------------
// Kernel 4: fused softmax + PV (fp32). Grid (st=32, n=12, b=2).
// Reads qk-scores (b,n,s,k) + relsc (b,s,n,k), sums, softmaxes, PV.
// ---------------------------------------------------------------------------
__global__ __launch_bounds__(256) void smpv_kernel(
    const float* __restrict__ scores, const float* __restrict__ relsc,
    const float* __restrict__ vws, float* __restrict__ out)
{
    __shared__ float sc[16][512];

    const int st  = blockIdx.x;
    const int n   = blockIdx.y;
    const int b   = blockIdx.z;
    const int s0  = st * 16;
    const int tid = threadIdx.x;

    const size_t base = (((size_t)(b * NH + n) * S_) + s0) * S_;

    #pragma unroll
    for (int j = 0; j < 8; ++j) {
        const int fidx = j * 256 + tid;
        const int row  = fidx >> 7;
        const int c4   = fidx & 127;
        float4 v = *(const float4*)(scores + base + (size_t)row * S_ + c4 * 4);
        float4 r = *(const float4*)(relsc +
                    (((size_t)(b * S_ + s0 + row)) * NH + n) * S_ + c4 * 4);
        v.x += r.x; v.y += r.y; v.z += r.z; v.w += r.w;
        *(float4*)&sc[row][c4 * 4] = v;
    }
    __syncthreads();

    const int w = tid >> 6, lane = tid & 63;

    for (int r = 0; r < 4; ++r) {
        const int row = w * 4 + r;
        float vals[8];
        float m = -1e30f;
        #pragma unroll
        for (int i = 0; i < 8; ++i) { vals[i] = sc[row][lane + 64 * i]; m = fmaxf(m, vals[i]); }
        #pragma unroll
        for (int off = 32; off >= 1; off >>= 1) m = fmaxf(m, __shfl_xor(m, off));
        float sum = 0.f;
        #pragma unroll
        for (int i = 0; i < 8; ++i) { vals[i] = __expf(vals[i] - m); sum += vals[i]; }
        #pragma unroll
        for (int off = 32; off >= 1; off >>= 1) sum += __shfl_xor(sum, off);
        const float inv = 1.0f / sum;
        #pragma unroll
        for (int i = 0; i < 8; ++i) sc[row][lane + 64 * i] = vals[i] * inv;
    }
    __syncthreads();

    float acc[4] = {0.f, 0.f, 0.f, 0.f};
    const float* vb = vws + (((size_t)(b * NH + n) * S_)) * HD + lane;
    for (int k = 0; k < S_; k += 4) {
        const float v0 = vb[(size_t)(k + 0) * HD];
        const float v1 = vb[(size_t)(k + 1) * HD];
        const float v2 = vb[(size_t)(k + 2) * HD];
        const float v3 = vb[(size_t)(k + 3) * HD];
        #pragma unroll
        for (int r = 0; r < 4; ++r) {
            float4 p = *(const float4*)&sc[w * 4 + r][k];
            acc[r] += p.x * v0 + p.y * v1 + p.z * v2 + p.w * v3;
        }
    }
    #pragma unroll
    for (int r = 0; r < 4; ++r)
        out[((size_t)(b * S_ + s0 + w * 4 + r)) * D_ + n * HD + lane] = acc[r];
}

extern "C" void kernel_launch(void* const* d_in, const int* in_sizes, int n_in,
                              void* d_out, int out_size, void* d_ws, size_t ws_size,
                              hipStream_t stream) {
    const float* hidden = (const float*)d_in[0];
    const float* mask   = (const float*)d_in[1];
    const float* rel1   = (const float*)d_in[2];
    const float* rel2   = (const float*)d_in[3];
    const float* rel3   = (const float*)d_in[4];
    const float* Wq     = (const float*)d_in[5];
    const float* bq     = (const float*)d_in[6];
    const float* Wk     = (const float*)d_in[7];
    const float* bk     = (const float*)d_in[8];
    const float* Wv     = (const float*)d_in[9];
    const float* bv     = (const float*)d_in[10];
    float* out = (float*)d_out;

    const size_t per = (size_t)B_ * NH * S_ * HD;   // 786432
    short* qbf    = (short*)d_ws;                    // 1.5 MB
    short* kbf    = qbf + per;                       // 1.5 MB
    float* vws    = (float*)(kbf + per);             // 3 MB
    float* scores = vws + per;                       // 25 MB  (b,n,s,k)
    float* relsc  = scores + (size_t)B_ * NH * S_ * S_;  // 12.6 MB (b,s,n,k)

    qkv_gemm<<<dim3(16, 12, 3), 256, 0, stream>>>(hidden, Wq, Wk, Wv, bq, bk, bv, qbf, kbf, vws);
    score_qk<<<dim3(8, 8, 24), 256, 0, stream>>>(qbf, kbf, mask, scores);
    score_rel<<<dim3(1024), 256, 0, stream>>>(qbf, rel1, rel2, rel3, relsc);
    smpv_kernel<<<dim3(S_ / 16, NH, B_), 256, 0, stream>>>(scores, relsc, vws, out);
}